// Round 14
// baseline (912.799 us; speedup 1.0000x reference)
//
#include <hip/hip_runtime.h>

#define T_STEPS 2048
#define HID 64

typedef __attribute__((ext_vector_type(4))) int int4v;

static __device__ __forceinline__ float exp2_f(float x) {
#if __has_builtin(__builtin_amdgcn_exp2f)
    return __builtin_amdgcn_exp2f(x);
#else
    return exp2f(x);
#endif
}
#define NLOG2E 1.4426950408889634f

// R14 = R13 (i8 K=64, one raw barrier/step, L0/L1 wave-specialized, skew 1)
// with 16 waves (1024 thr, 4 waves/SIMD) and half-width tiles:
//   each wave owns 8 units; MFMA-P cols = {i,f} x 8 units, MFMA-Q = {g,o} x 8.
//   L0 = 2 MFMA/step (was 4), L1 = 4 chained (was 8); per SIMD still 12 MFMA
//   (220 cy) but 4 waves interleave -> ds_read/act latency hidden.
// Lane (lg,l15): C row 4lg (reg 0) = batch lg&1; gets gates (l15<8 ? {i,g}
// : {f,o}) of unit base+(l15&7); shfl_xor(8) pair merges all 4 gates.
// Bias rides the MFMA C operand as i32 (exact to +-0.5 dq). L1 uses a shared
// per-gate-row scale for Wih1/Whh1 -> the two MFMAs CHAIN in i32 (dequant =
// 1 cvt + 1 mul). h quantized at fixed 127; x-path f32 exact; c-state f32.
__global__ void __launch_bounds__(1024, 1) __attribute__((amdgpu_waves_per_eu(4, 4)))
lstm2_w16(const float* __restrict__ x,
          const float* __restrict__ wih0, const float* __restrict__ whh0,
          const float* __restrict__ bih0, const float* __restrict__ bhh0,
          const float* __restrict__ wih1, const float* __restrict__ whh1,
          const float* __restrict__ bih1, const float* __restrict__ bhh1,
          float* __restrict__ out, int B)
{
    __shared__ __align__(16) char s_h0q[2][2][HID];   // [pingpong][batch][unit] i8
    __shared__ __align__(16) char s_h1q[2][2][HID];
    __shared__ __align__(16) float s_xf[2 * T_STEPS * 4];   // 64 KB x f32

    const int tid  = threadIdx.x;
    const int lane = tid & 63;
    const int wv   = tid >> 6;        // wave 0..15
    const int wg   = wv >> 3;         // 0 = L0 group (waves 0-7), 1 = L1
    const int wl   = wv & 7;          // wave-within-group
    const int base = 8 * wl;          // this wave's 8 units
    const int l15  = lane & 15;
    const int lg   = lane >> 4;
    const int l8   = l15 & 7;         // unit within wave
    const int h8   = l15 >> 3;        // 0: lane holds {i,g}; 1: {f,o}
    const int b0   = 2 * blockIdx.x;
    const int bx   = lg & 1;          // this lane's batch
    const int rsel = (l15 >> 2) & 1;  // A rows 0,8 -> b0; 4,12 -> b1
    const int un   = base + l8;       // this lane's unit

    const float SCL[4] = {-NLOG2E, -NLOG2E, -2.0f * NLOG2E, -NLOG2E};
    const int   tP = h8;              // gate type of P value (i or f) - sigmoid
    const int   tQ = 2 + h8;          // gate type of Q value (g or o)
    const int   rP = 64 * tP + un;    // gate rows
    const int   rQ = 64 * tQ + un;
    const float aselQ = h8 ? 1.0f : 2.0f;   // Q act: aselQ*rcp(1+2^s)+cselQ
    const float cselQ = h8 ? 0.0f : -1.0f;

    // ---------------- stage x, zero h ----------------
    const float4* __restrict__ xb4 = (const float4*)(x + (size_t)b0 * (T_STEPS * 4));
    float4* s_xf4 = (float4*)s_xf;
    for (int i2 = tid; i2 < 2 * T_STEPS; i2 += 1024) s_xf4[i2] = xb4[i2];
    if (tid < 256) {
        ((char*)s_h0q)[tid] = 0;
        ((char*)s_h1q)[tid] = 0;
    }

    const size_t BTH = (size_t)B * T_STEPS * HID;
    const size_t BH  = (size_t)B * HID;

    auto pack16 = [&](const float* wr, float qs) {
        int4v r;
        #pragma unroll
        for (int dw = 0; dw < 4; ++dw) {
            unsigned d = 0;
            #pragma unroll
            for (int bb = 0; bb < 4; ++bb) {
                int q = (int)rintf(wr[dw * 4 + bb] * qs);
                d |= ((unsigned)(q & 255)) << (8 * bb);
            }
            r[dw] = (int)d;
        }
        return r;
    };

    #define BAR() do { asm volatile("s_waitcnt lgkmcnt(0)" ::: "memory"); \
                       __builtin_amdgcn_s_barrier(); } while (0)

    if (wg == 0) {
        // =================== layer0 wave group (8 waves x 8 units) ===================
        float wrP[16], wrQ[16];
        #pragma unroll
        for (int j = 0; j < 16; ++j) {
            wrP[j] = whh0[rP * HID + 16 * lg + j];
            wrQ[j] = whh0[rQ * HID + 16 * lg + j];
        }
        float mxP = 0.f, mxQ = 0.f;
        #pragma unroll
        for (int j = 0; j < 16; ++j) {
            mxP = fmaxf(mxP, fabsf(wrP[j]));
            mxQ = fmaxf(mxQ, fabsf(wrQ[j]));
        }
        mxP = fmaxf(mxP, __shfl_xor(mxP, 16)); mxP = fmaxf(mxP, __shfl_xor(mxP, 32));
        mxQ = fmaxf(mxQ, __shfl_xor(mxQ, 16)); mxQ = fmaxf(mxQ, __shfl_xor(mxQ, 32));
        mxP = fmaxf(mxP, 1e-20f); mxQ = fmaxf(mxQ, 1e-20f);
        const int4v WPq = pack16(wrP, 127.f / mxP);
        const int4v WQq = pack16(wrQ, 127.f / mxQ);
        const float dqP = (mxP / 16129.f) * SCL[tP];
        const float dqQ = (mxQ / 16129.f) * SCL[tQ];
        const int bP = (int)rintf((bih0[rP] + bhh0[rP]) * 16129.f / mxP);
        const int bQ = (int)rintf((bih0[rQ] + bhh0[rQ]) * 16129.f / mxQ);
        const int4v BiasP = {bP, bP, bP, bP};
        const int4v BiasQ = {bQ, bQ, bQ, bQ};
        float wxP[4], wxQ[4];
        #pragma unroll
        for (int j = 0; j < 4; ++j) {
            wxP[j] = wih0[rP * 4 + j] * SCL[tP];
            wxQ[j] = wih0[rQ * 4 + j] * SCL[tQ];
        }
        float c0s = 0.f, h0s = 0.f;
        const float* xcur = &s_xf[(size_t)bx * T_STEPS * 4];
        __syncthreads();

        auto l0_body = [&](int P) {
            const int Q = P ^ 1;
            const int4v Ha = *(const int4v*)&s_h0q[Q][rsel][16 * lg];  // h0(t-1)
            const float4 xt = *(const float4*)xcur;  xcur += 4;
            __builtin_amdgcn_s_setprio(1);
            int4v aP = __builtin_amdgcn_mfma_i32_16x16x64_i8(Ha, WPq, BiasP, 0, 0, 0);
            int4v aQ = __builtin_amdgcn_mfma_i32_16x16x64_i8(Ha, WQq, BiasQ, 0, 0, 0);
            __builtin_amdgcn_s_setprio(0);
            float xP = wxP[0] * xt.x;
            float xQ = wxQ[0] * xt.x;
            xP = fmaf(wxP[1], xt.y, xP); xP = fmaf(wxP[2], xt.z, xP); xP = fmaf(wxP[3], xt.w, xP);
            xQ = fmaf(wxQ[1], xt.y, xQ); xQ = fmaf(wxQ[2], xt.z, xQ); xQ = fmaf(wxQ[3], xt.w, xQ);
            float sP = fmaf((float)aP[0], dqP, xP);
            float sQ = fmaf((float)aQ[0], dqQ, xQ);
            float oP = __shfl_xor(sP, 8);
            float oQ = __shfl_xor(sQ, 8);
            float ip = h8 ? oP : sP;
            float fp = h8 ? sP : oP;
            float gp = h8 ? oQ : sQ;
            float op = h8 ? sQ : oQ;
            float i_ = __builtin_amdgcn_rcpf(1.0f + exp2_f(ip));
            float f_ = __builtin_amdgcn_rcpf(1.0f + exp2_f(fp));
            float g_ = fmaf(2.0f, __builtin_amdgcn_rcpf(1.0f + exp2_f(gp)), -1.0f);
            float o_ = __builtin_amdgcn_rcpf(1.0f + exp2_f(op));
            c0s = fmaf(f_, c0s, i_ * g_);
            h0s = o_ * fmaf(2.0f, __builtin_amdgcn_rcpf(1.0f + exp2_f(c0s * (-2.0f * NLOG2E))), -1.0f);
            if (lg < 2 && l15 < 8) s_h0q[P][lg][un] = (char)(int)rintf(h0s * 127.f);
        };

        for (int it = 0; it < T_STEPS / 2; ++it) {
            l0_body(0); BAR();
            l0_body(1); BAR();
        }
        if (lg < 2 && l15 < 8) {
            const size_t bi = (size_t)(b0 + lg) * HID + un;
            out[BTH + bi]          = h0s;   // h_n layer0
            out[BTH + 2 * BH + bi] = c0s;   // c_n layer0
        }
    } else {
        // =================== layer1 wave group (8 waves x 8 units) ===================
        float wiP[16], whP[16], wiQ[16], whQ[16];
        #pragma unroll
        for (int j = 0; j < 16; ++j) {
            wiP[j] = wih1[rP * HID + 16 * lg + j];
            whP[j] = whh1[rP * HID + 16 * lg + j];
            wiQ[j] = wih1[rQ * HID + 16 * lg + j];
            whQ[j] = whh1[rQ * HID + 16 * lg + j];
        }
        float mxP = 0.f, mxQ = 0.f;
        #pragma unroll
        for (int j = 0; j < 16; ++j) {
            mxP = fmaxf(mxP, fmaxf(fabsf(wiP[j]), fabsf(whP[j])));
            mxQ = fmaxf(mxQ, fmaxf(fabsf(wiQ[j]), fabsf(whQ[j])));
        }
        mxP = fmaxf(mxP, __shfl_xor(mxP, 16)); mxP = fmaxf(mxP, __shfl_xor(mxP, 32));
        mxQ = fmaxf(mxQ, __shfl_xor(mxQ, 16)); mxQ = fmaxf(mxQ, __shfl_xor(mxQ, 32));
        mxP = fmaxf(mxP, 1e-20f); mxQ = fmaxf(mxQ, 1e-20f);
        const int4v WPi = pack16(wiP, 127.f / mxP);
        const int4v WPh = pack16(whP, 127.f / mxP);   // shared scale -> i32 chain ok
        const int4v WQi = pack16(wiQ, 127.f / mxQ);
        const int4v WQh = pack16(whQ, 127.f / mxQ);
        const float dqP = (mxP / 16129.f) * SCL[tP];
        const float dqQ = (mxQ / 16129.f) * SCL[tQ];
        const int bP = (int)rintf((bih1[rP] + bhh1[rP]) * 16129.f / mxP);
        const int bQ = (int)rintf((bih1[rQ] + bhh1[rQ]) * 16129.f / mxQ);
        const int4v BiasP = {bP, bP, bP, bP};
        const int4v BiasQ = {bQ, bQ, bQ, bQ};
        float c1s = 0.f, h1s = 0.f;
        float* __restrict__ opp = out + (size_t)(b0 + bx) * T_STEPS * HID + un;
        __syncthreads();
        BAR();   // matches L0's first barrier (L1 idle in window 0)

        auto l1_body = [&](int P) {
            const int Q = P ^ 1;
            const int4v Ha = *(const int4v*)&s_h0q[Q][rsel][16 * lg];  // h0(t)
            const int4v Ga = *(const int4v*)&s_h1q[Q][rsel][16 * lg];  // h1(t-1)
            __builtin_amdgcn_s_setprio(1);
            int4v p1 = __builtin_amdgcn_mfma_i32_16x16x64_i8(Ha, WPi, BiasP, 0, 0, 0);
            int4v q1 = __builtin_amdgcn_mfma_i32_16x16x64_i8(Ha, WQi, BiasQ, 0, 0, 0);
            int4v p2 = __builtin_amdgcn_mfma_i32_16x16x64_i8(Ga, WPh, p1, 0, 0, 0);
            int4v q2 = __builtin_amdgcn_mfma_i32_16x16x64_i8(Ga, WQh, q1, 0, 0, 0);
            __builtin_amdgcn_s_setprio(0);
            float sP = (float)p2[0] * dqP;
            float sQ = (float)q2[0] * dqQ;
            float oP = __shfl_xor(sP, 8);
            float oQ = __shfl_xor(sQ, 8);
            float ip = h8 ? oP : sP;
            float fp = h8 ? sP : oP;
            float gp = h8 ? oQ : sQ;
            float op = h8 ? sQ : oQ;
            float i_ = __builtin_amdgcn_rcpf(1.0f + exp2_f(ip));
            float f_ = __builtin_amdgcn_rcpf(1.0f + exp2_f(fp));
            float g_ = fmaf(2.0f, __builtin_amdgcn_rcpf(1.0f + exp2_f(gp)), -1.0f);
            float o_ = __builtin_amdgcn_rcpf(1.0f + exp2_f(op));
            c1s = fmaf(f_, c1s, i_ * g_);
            h1s = o_ * fmaf(2.0f, __builtin_amdgcn_rcpf(1.0f + exp2_f(c1s * (-2.0f * NLOG2E))), -1.0f);
            if (lg < 2 && l15 < 8) {
                s_h1q[P][lg][un] = (char)(int)rintf(h1s * 127.f);
                *opp = h1s;                  // out1 f32; stays in flight across BAR
            }
            opp += HID;
        };

        for (int it = 0; it < T_STEPS / 2 - 1; ++it) {
            l1_body(1); BAR();
            l1_body(0); BAR();
        }
        l1_body(1); BAR();
        l1_body(0);                          // last step, no barrier
        if (lg < 2 && l15 < 8) {
            const size_t bi = (size_t)(b0 + lg) * HID + un;
            out[BTH + BH + bi]     = h1s;   // h_n layer1
            out[BTH + 3 * BH + bi] = c1s;   // c_n layer1
        }
    }
    #undef BAR
}

extern "C" void kernel_launch(void* const* d_in, const int* in_sizes, int n_in,
                              void* d_out, int out_size, void* d_ws, size_t ws_size,
                              hipStream_t stream) {
    const float* x    = (const float*)d_in[0];
    const float* wih0 = (const float*)d_in[1];
    const float* whh0 = (const float*)d_in[2];
    const float* bih0 = (const float*)d_in[3];
    const float* bhh0 = (const float*)d_in[4];
    const float* wih1 = (const float*)d_in[5];
    const float* whh1 = (const float*)d_in[6];
    const float* bih1 = (const float*)d_in[7];
    const float* bhh1 = (const float*)d_in[8];
    float* out = (float*)d_out;

    const int B = in_sizes[0] / (T_STEPS * 4);   // 512

    lstm2_w16<<<dim3(B / 2), dim3(1024), 0, stream>>>(
        x, wih0, whh0, bih0, bhh0, wih1, whh1, bih1, bhh1, out, B);
}

// Round 15
// 640.332 us; speedup vs baseline: 1.4255x; 1.4255x over previous
//
#include <hip/hip_runtime.h>

#define T_STEPS 2048
#define HID 64

typedef __attribute__((ext_vector_type(4))) int int4v;

static __device__ __forceinline__ float exp2_f(float x) {
#if __has_builtin(__builtin_amdgcn_exp2f)
    return __builtin_amdgcn_exp2f(x);
#else
    return exp2f(x);
#endif
}
#define NLOG2E 1.4426950408889634f

// R15 = R13 (i8 K=64, wave-specialized, 1 raw barrier/interval) +
//  (1) L1 skew deepened to 2 steps with REGISTER PREFETCH of its h0 operand:
//      h0(s) for L1-step s=t-2 is stable since barrier t-1, so it is
//      ds_read into regs during interval t-1 -> at interval start the L1
//      wave issues 4 MFMAs immediately, covering L0's ds_read stall (the
//      ~120cy interval-start hole identified in R13's 370cy latency gap).
//      h0 slots depth-4 (L0 writes t&3, reads (t-1)&3; L1 prefetches
//      (t-1)&3 -- all distinct, barrier-separated). h1 stays depth-2.
//  (2) L1 shared per-gate-row scale (max over Wih1,Whh1 rows) -> the two
//      MFMAs chain in i32 with bias in C; dequant = 1 cvt + 1 mul per gate
//      (R14 measured absmax 5.9e-3 with this -- safe).
// L0 is R13-verbatim (per-row scales, x-path f32, acts in exp2 form).
__global__ void __launch_bounds__(512, 1) __attribute__((amdgpu_waves_per_eu(2, 2)))
lstm2_sk2(const float* __restrict__ x,
          const float* __restrict__ wih0, const float* __restrict__ whh0,
          const float* __restrict__ bih0, const float* __restrict__ bhh0,
          const float* __restrict__ wih1, const float* __restrict__ whh1,
          const float* __restrict__ bih1, const float* __restrict__ bhh1,
          float* __restrict__ out, int B)
{
    __shared__ __align__(16) char s_h0q[4][2][HID];   // depth-4 [slot][batch][unit]
    __shared__ __align__(16) char s_h1q[2][2][HID];   // depth-2
    __shared__ __align__(16) float s_xf[2 * T_STEPS * 4];   // 64 KB x f32

    const int tid  = threadIdx.x;
    const int lane = tid & 63;
    const int wv   = tid >> 6;       // wave 0..7
    const int wg   = wv >> 2;        // 0 = L0 group, 1 = L1 group
    const int wl   = wv & 3;         // units 16wl..16wl+15
    const int l15  = lane & 15;
    const int lg   = lane >> 4;      // k-block; lg0/1 = batch0/1 for acts
    const int b0   = 2 * blockIdx.x;
    const int u    = 16 * wl + l15;
    const int bx   = lg & 1;
    const int rsel = (l15 >> 2) & 1; // A rows 0,8 -> b0; 4,12 -> b1

    const float SCL[4] = {-NLOG2E, -NLOG2E, -2.0f * NLOG2E, -NLOG2E};

    // ---------------- stage x, zero h ----------------
    const float4* __restrict__ xb4 = (const float4*)(x + (size_t)b0 * (T_STEPS * 4));
    float4* s_xf4 = (float4*)s_xf;
    for (int i2 = tid; i2 < 2 * T_STEPS; i2 += 512) s_xf4[i2] = xb4[i2];
    if (tid < 256) {
        ((char*)s_h0q)[tid] = 0; ((char*)s_h0q)[tid + 256] = 0;  // 4 slots = 512 B
        ((char*)s_h1q)[tid] = 0;                                  // 2 slots = 256 B
    }

    const size_t BTH = (size_t)B * T_STEPS * HID;
    const size_t BH  = (size_t)B * HID;
    const size_t bi  = (size_t)(b0 + bx) * HID + u;
    const int4v Zi = {0, 0, 0, 0};

    auto pack16 = [&](const float* wr, float qs) {
        int4v r;
        #pragma unroll
        for (int dw = 0; dw < 4; ++dw) {
            unsigned d = 0;
            #pragma unroll
            for (int bbb = 0; bbb < 4; ++bbb) {
                int q = (int)rintf(wr[dw * 4 + bbb] * qs);
                d |= ((unsigned)(q & 255)) << (8 * bbb);
            }
            r[dw] = (int)d;
        }
        return r;
    };

    #define BAR() do { asm volatile("s_waitcnt lgkmcnt(0)" ::: "memory"); \
                       __builtin_amdgcn_s_barrier(); } while (0)

    if (wg == 0) {
        // =================== layer0 wave group (R13-verbatim, depth-4 slots) ===================
        int4v W0q[4];
        float dq0[4];
        float wx[4][4];
        float b0s[4];
        #pragma unroll
        for (int ni = 0; ni < 4; ++ni) {
            const int g = 64 * ni + u;
            float wr[16];
            #pragma unroll
            for (int j = 0; j < 16; ++j) wr[j] = whh0[g * HID + 16 * lg + j];
            float mx = 0.f;
            #pragma unroll
            for (int j = 0; j < 16; ++j) mx = fmaxf(mx, fabsf(wr[j]));
            mx = fmaxf(mx, __shfl_xor(mx, 16));
            mx = fmaxf(mx, __shfl_xor(mx, 32));
            mx = fmaxf(mx, 1e-20f);
            W0q[ni] = pack16(wr, 127.f / mx);
            dq0[ni] = (mx / 16129.f) * SCL[ni];
            #pragma unroll
            for (int j = 0; j < 4; ++j) wx[ni][j] = wih0[g * 4 + j] * SCL[ni];
            b0s[ni] = (bih0[g] + bhh0[g]) * SCL[ni];
        }
        float c0s = 0.f, h0s = 0.f;
        const float* xcur = &s_xf[(size_t)bx * T_STEPS * 4];
        __syncthreads();   // staging visible

        auto l0_step = [&](int RD, int WR) {
            const int4v Ha = *(const int4v*)&s_h0q[RD][rsel][16 * lg];  // h0(t-1)
            const float4 xt = *(const float4*)xcur;  xcur += 4;
            __builtin_amdgcn_s_setprio(1);
            int4v a0 = __builtin_amdgcn_mfma_i32_16x16x64_i8(Ha, W0q[0], Zi, 0, 0, 0);
            int4v a1 = __builtin_amdgcn_mfma_i32_16x16x64_i8(Ha, W0q[1], Zi, 0, 0, 0);
            int4v a2 = __builtin_amdgcn_mfma_i32_16x16x64_i8(Ha, W0q[2], Zi, 0, 0, 0);
            int4v a3 = __builtin_amdgcn_mfma_i32_16x16x64_i8(Ha, W0q[3], Zi, 0, 0, 0);
            __builtin_amdgcn_s_setprio(0);
            float t0 = fmaf(wx[0][0], xt.x, b0s[0]);
            float t1 = fmaf(wx[1][0], xt.x, b0s[1]);
            float t2 = fmaf(wx[2][0], xt.x, b0s[2]);
            float t3 = fmaf(wx[3][0], xt.x, b0s[3]);
            t0 = fmaf(wx[0][1], xt.y, t0); t0 = fmaf(wx[0][2], xt.z, t0); t0 = fmaf(wx[0][3], xt.w, t0);
            t1 = fmaf(wx[1][1], xt.y, t1); t1 = fmaf(wx[1][2], xt.z, t1); t1 = fmaf(wx[1][3], xt.w, t1);
            t2 = fmaf(wx[2][1], xt.y, t2); t2 = fmaf(wx[2][2], xt.z, t2); t2 = fmaf(wx[2][3], xt.w, t2);
            t3 = fmaf(wx[3][1], xt.y, t3); t3 = fmaf(wx[3][2], xt.z, t3); t3 = fmaf(wx[3][3], xt.w, t3);
            float s0 = fmaf((float)a0[0], dq0[0], t0);
            float s1 = fmaf((float)a1[0], dq0[1], t1);
            float s2 = fmaf((float)a2[0], dq0[2], t2);
            float s3 = fmaf((float)a3[0], dq0[3], t3);
            float i_ = __builtin_amdgcn_rcpf(1.0f + exp2_f(s0));
            float f_ = __builtin_amdgcn_rcpf(1.0f + exp2_f(s1));
            float g_ = fmaf(2.0f, __builtin_amdgcn_rcpf(1.0f + exp2_f(s2)), -1.0f);
            float o_ = __builtin_amdgcn_rcpf(1.0f + exp2_f(s3));
            c0s = fmaf(f_, c0s, i_ * g_);
            h0s = o_ * fmaf(2.0f, __builtin_amdgcn_rcpf(1.0f + exp2_f(c0s * (-2.0f * NLOG2E))), -1.0f);
            if (lg < 2) s_h0q[WR][lg][u] = (char)(int)rintf(h0s * 127.f);
        };

        l0_step(3, 0); BAR();      // step 0 (interval 0)
        l0_step(0, 1); BAR();      // step 1
        for (int it = 0; it < 511; ++it) {      // steps 2..2045
            l0_step(1, 2); BAR();
            l0_step(2, 3); BAR();
            l0_step(3, 0); BAR();
            l0_step(0, 1); BAR();
        }
        l0_step(1, 2); BAR();      // step 2046
        l0_step(2, 3); BAR();      // step 2047
        BAR();                      // interval 2048 (L1 still working)
        // interval 2049 has no trailing barrier
        if (lg < 2) {
            out[BTH + bi]          = h0s;   // h_n layer0
            out[BTH + 2 * BH + bi] = c0s;   // c_n layer0
        }
    } else {
        // =================== layer1 wave group (skew 2, prefetched h0) ===================
        int4v Wihq[4], Whhq[4], BiasI[4];
        float dq1[4];
        #pragma unroll
        for (int ni = 0; ni < 4; ++ni) {
            const int g = 64 * ni + u;
            float wi[16], wh[16];
            #pragma unroll
            for (int j = 0; j < 16; ++j) {
                wi[j] = wih1[g * HID + 16 * lg + j];
                wh[j] = whh1[g * HID + 16 * lg + j];
            }
            float mx = 0.f;
            #pragma unroll
            for (int j = 0; j < 16; ++j) mx = fmaxf(mx, fmaxf(fabsf(wi[j]), fabsf(wh[j])));
            mx = fmaxf(mx, __shfl_xor(mx, 16));
            mx = fmaxf(mx, __shfl_xor(mx, 32));
            mx = fmaxf(mx, 1e-20f);
            Wihq[ni] = pack16(wi, 127.f / mx);
            Whhq[ni] = pack16(wh, 127.f / mx);   // shared scale -> i32 chaining valid
            dq1[ni]  = (mx / 16129.f) * SCL[ni];
            const int bq = (int)rintf((bih1[g] + bhh1[g]) * 16129.f / mx);
            BiasI[ni] = (int4v){bq, bq, bq, bq};
        }
        float c1s = 0.f, h1s = 0.f;
        float* __restrict__ opp = out + (size_t)(b0 + bx) * T_STEPS * HID + u;
        int4v Hp;   // prefetched h0(s) operand for the NEXT interval's L1 step
        __syncthreads();   // staging visible
        BAR();             // interval 0 (idle)
        Hp = *(const int4v*)&s_h0q[0][rsel][16 * lg];   // prefetch h0(0)
        BAR();             // interval 1 (drains the prefetch)

        // interval t: computes L1 step s=t-2 using Hp (=h0(s)); reads h1(s-1)
        // from slot RH=(t&1)^1, writes h1(s) to WH=t&1; prefetches h0 slot PF=(t-1)&3.
        auto l1_step = [&](int RH, int WH, int PF) {
            const int4v Ga = *(const int4v*)&s_h1q[RH][rsel][16 * lg];  // h1(s-1)
            __builtin_amdgcn_s_setprio(1);
            int4v p0 = __builtin_amdgcn_mfma_i32_16x16x64_i8(Hp, Wihq[0], BiasI[0], 0, 0, 0);
            int4v p1 = __builtin_amdgcn_mfma_i32_16x16x64_i8(Hp, Wihq[1], BiasI[1], 0, 0, 0);
            int4v p2 = __builtin_amdgcn_mfma_i32_16x16x64_i8(Hp, Wihq[2], BiasI[2], 0, 0, 0);
            int4v p3 = __builtin_amdgcn_mfma_i32_16x16x64_i8(Hp, Wihq[3], BiasI[3], 0, 0, 0);
            p0 = __builtin_amdgcn_mfma_i32_16x16x64_i8(Ga, Whhq[0], p0, 0, 0, 0);
            p1 = __builtin_amdgcn_mfma_i32_16x16x64_i8(Ga, Whhq[1], p1, 0, 0, 0);
            p2 = __builtin_amdgcn_mfma_i32_16x16x64_i8(Ga, Whhq[2], p2, 0, 0, 0);
            p3 = __builtin_amdgcn_mfma_i32_16x16x64_i8(Ga, Whhq[3], p3, 0, 0, 0);
            __builtin_amdgcn_s_setprio(0);
            float s0 = (float)p0[0] * dq1[0];
            float s1 = (float)p1[0] * dq1[1];
            float s2 = (float)p2[0] * dq1[2];
            float s3 = (float)p3[0] * dq1[3];
            float i_ = __builtin_amdgcn_rcpf(1.0f + exp2_f(s0));
            float f_ = __builtin_amdgcn_rcpf(1.0f + exp2_f(s1));
            float g_ = fmaf(2.0f, __builtin_amdgcn_rcpf(1.0f + exp2_f(s2)), -1.0f);
            float o_ = __builtin_amdgcn_rcpf(1.0f + exp2_f(s3));
            c1s = fmaf(f_, c1s, i_ * g_);
            h1s = o_ * fmaf(2.0f, __builtin_amdgcn_rcpf(1.0f + exp2_f(c1s * (-2.0f * NLOG2E))), -1.0f);
            if (lg < 2) {
                s_h1q[WH][lg][u] = (char)(int)rintf(h1s * 127.f);
                *opp = h1s;                  // out1[b,s]; stays in flight across BAR
            }
            opp += HID;
            if (PF >= 0) Hp = *(const int4v*)&s_h0q[PF][rsel][16 * lg];
        };

        for (int it = 0; it < 511; ++it) {      // intervals 2..2045, steps 0..2043
            l1_step(1, 0, 1); BAR();   // t=4k+2
            l1_step(0, 1, 2); BAR();   // t=4k+3
            l1_step(1, 0, 3); BAR();   // t=4k+4
            l1_step(0, 1, 0); BAR();   // t=4k+5
        }
        l1_step(1, 0, 1); BAR();   // interval 2046, step 2044
        l1_step(0, 1, 2); BAR();   // interval 2047, step 2045
        l1_step(1, 0, 3); BAR();   // interval 2048, step 2046
        l1_step(0, 1, -1);         // interval 2049, step 2047, no prefetch/barrier
        if (lg < 2) {
            out[BTH + BH + bi]     = h1s;   // h_n layer1
            out[BTH + 3 * BH + bi] = c1s;   // c_n layer1
        }
    }
    #undef BAR
}

extern "C" void kernel_launch(void* const* d_in, const int* in_sizes, int n_in,
                              void* d_out, int out_size, void* d_ws, size_t ws_size,
                              hipStream_t stream) {
    const float* x    = (const float*)d_in[0];
    const float* wih0 = (const float*)d_in[1];
    const float* whh0 = (const float*)d_in[2];
    const float* bih0 = (const float*)d_in[3];
    const float* bhh0 = (const float*)d_in[4];
    const float* wih1 = (const float*)d_in[5];
    const float* whh1 = (const float*)d_in[6];
    const float* bih1 = (const float*)d_in[7];
    const float* bhh1 = (const float*)d_in[8];
    float* out = (float*)d_out;

    const int B = in_sizes[0] / (T_STEPS * 4);   // 512

    lstm2_sk2<<<dim3(B / 2), dim3(512), 0, stream>>>(
        x, wih0, whh0, bih0, bhh0, wih1, whh1, bih1, bhh1, out, B);
}